// Round 1
// baseline (1270.109 us; speedup 1.0000x reference)
//
#include <hip/hip_runtime.h>
#include <hip/hip_bf16.h>

// Problem constants (from reference)
#define N_NODES 100000
#define N_EDGES 1600000
#define N_RELS  8
#define IN_F    64
#define HID_F   64
#define OUT_F   32
#define NSEG    (N_NODES * N_RELS)      // 800000 (node, rel) segments
#define SCAN_EPB 1024                   // elements per scan block (256 thr x 4)
#define SCAN_NB  ((NSEG + SCAN_EPB - 1) / SCAN_EPB)  // 782

// ---------------------------------------------------------------------------
// 1) Histogram: cnt[dst*8+etype] += 1
// ---------------------------------------------------------------------------
__global__ void k_hist(const int* __restrict__ dst, const int* __restrict__ et,
                       int* __restrict__ cnt) {
    int e = blockIdx.x * blockDim.x + threadIdx.x;
    if (e < N_EDGES) {
        int seg = dst[e] * N_RELS + et[e];
        atomicAdd(&cnt[seg], 1);
    }
}

// ---------------------------------------------------------------------------
// 2a) Scan pass A: per-block sums (1024 elems / block, 256 threads x 4)
// ---------------------------------------------------------------------------
__global__ void k_scanA(const int* __restrict__ cnt, int* __restrict__ bsums) {
    __shared__ int red[256];
    int t = threadIdx.x;
    int base = blockIdx.x * SCAN_EPB + t * 4;
    int s = 0;
    #pragma unroll
    for (int j = 0; j < 4; ++j) {
        int idx = base + j;
        if (idx < NSEG) s += cnt[idx];
    }
    red[t] = s;
    __syncthreads();
    for (int st = 128; st > 0; st >>= 1) {
        if (t < st) red[t] += red[t + st];
        __syncthreads();
    }
    if (t == 0) bsums[blockIdx.x] = red[0];
}

// ---------------------------------------------------------------------------
// 2b) Scan pass B: exclusive scan of block sums (NB=782 <= 1024), one block
// ---------------------------------------------------------------------------
__global__ void k_scanB(int* __restrict__ bsums) {
    __shared__ int s[1024];
    int t = threadIdx.x;
    int own = (t < SCAN_NB) ? bsums[t] : 0;
    s[t] = own;
    __syncthreads();
    for (int off = 1; off < 1024; off <<= 1) {
        int v = (t >= off) ? s[t - off] : 0;
        __syncthreads();
        s[t] += v;
        __syncthreads();
    }
    if (t < SCAN_NB) bsums[t] = s[t] - own;   // exclusive
}

// ---------------------------------------------------------------------------
// 2c) Scan pass C: per-element exclusive offsets = blockBase + local prefix
// ---------------------------------------------------------------------------
__global__ void k_scanC(const int* __restrict__ cnt, const int* __restrict__ bsums,
                        int* __restrict__ offs) {
    __shared__ int ts[256];
    int t = threadIdx.x;
    int base = blockIdx.x * SCAN_EPB + t * 4;
    int v[4];
    int local = 0;
    #pragma unroll
    for (int j = 0; j < 4; ++j) {
        int idx = base + j;
        v[j] = (idx < NSEG) ? cnt[idx] : 0;
        local += v[j];
    }
    ts[t] = local;
    __syncthreads();
    for (int off = 1; off < 256; off <<= 1) {
        int x = (t >= off) ? ts[t - off] : 0;
        __syncthreads();
        ts[t] += x;
        __syncthreads();
    }
    int run = bsums[blockIdx.x] + (ts[t] - local);  // exclusive start for this thread
    #pragma unroll
    for (int j = 0; j < 4; ++j) {
        int idx = base + j;
        if (idx < NSEG) offs[idx] = run;
        run += v[j];
    }
}

// ---------------------------------------------------------------------------
// 3) Scatter edges into seg-sorted order: sortedSrc[offs[seg] + cursor++] = src
// ---------------------------------------------------------------------------
__global__ void k_scatter(const int* __restrict__ src, const int* __restrict__ dst,
                          const int* __restrict__ et, const int* __restrict__ offs,
                          int* __restrict__ cursor, int* __restrict__ ssrc) {
    int e = blockIdx.x * blockDim.x + threadIdx.x;
    if (e < N_EDGES) {
        int seg = dst[e] * N_RELS + et[e];
        int pos = offs[seg] + atomicAdd(&cursor[seg], 1);
        ssrc[pos] = src[e];
    }
}

// ---------------------------------------------------------------------------
// 4) Fused layer: per-(node,rel) mean aggregation + [576]x[576,NOUT] GEMV
//    Block = 512 threads handles 8 nodes.
//    Phase 1: wave r aggregates relation r (lane = feature), -> LDS s[8][576]
//             (last 64 of the 576 are the node's own features for the root term)
//    Phase 2: wave w handles k-chunk [w*64, w*64+64); wave 0 also does the
//             root chunk [512,576). Partials to LDS, then reduce + bias(+ReLU).
// ---------------------------------------------------------------------------
template <int NOUT, bool RELU>
__global__ __launch_bounds__(512) void k_layer(
        const float* __restrict__ xin, const int* __restrict__ offs,
        const int* __restrict__ cnt, const int* __restrict__ ssrc,
        const float* __restrict__ Wm, const float* __restrict__ rootm,
        const float* __restrict__ bias, float* __restrict__ out) {
    __shared__ float slds[8][576];
    __shared__ float pl[8][8][64];   // [wave][node g][o]

    const int tid = threadIdx.x;
    const int r = tid >> 6;          // wave index == relation in phase 1
    const int f = tid & 63;          // lane == feature / output col
    const int node0 = blockIdx.x * 8;

    // ---- Phase 1: aggregation ----
    for (int g = 0; g < 8; ++g) {
        int node = node0 + g;
        int seg = node * N_RELS + r;
        int start = offs[seg];
        int c = cnt[seg];
        float acc = 0.0f;
        for (int e = 0; e < c; ++e) {
            int s = ssrc[start + e];           // wave-uniform
            acc += xin[s * 64 + f];            // coalesced 256B
        }
        float norm = 1.0f / (float)max(c, 1);
        slds[g][r * 64 + f] = acc * norm;
        if (r == 0) slds[g][512 + f] = xin[node * 64 + f];
    }
    __syncthreads();

    // ---- Phase 2: GEMV, k-partitioned across the 8 waves ----
    const int oidx = (f < NOUT) ? f : 0;   // safe weight column
    float acc[8];
    #pragma unroll
    for (int g = 0; g < 8; ++g) acc[g] = 0.0f;

    const int kb = r * 64;
    #pragma unroll 4
    for (int kk = 0; kk < 64; kk += 4) {
        int k = kb + kk;
        float w0 = Wm[(k + 0) * NOUT + oidx];
        float w1 = Wm[(k + 1) * NOUT + oidx];
        float w2 = Wm[(k + 2) * NOUT + oidx];
        float w3 = Wm[(k + 3) * NOUT + oidx];
        #pragma unroll
        for (int g = 0; g < 8; ++g) {
            float4 s4 = *(const float4*)&slds[g][k];
            acc[g] = fmaf(s4.x, w0, acc[g]);
            acc[g] = fmaf(s4.y, w1, acc[g]);
            acc[g] = fmaf(s4.z, w2, acc[g]);
            acc[g] = fmaf(s4.w, w3, acc[g]);
        }
    }
    if (r == 0) {  // root chunk k in [512, 576)
        #pragma unroll 4
        for (int kk = 0; kk < 64; kk += 4) {
            float w0 = rootm[(kk + 0) * NOUT + oidx];
            float w1 = rootm[(kk + 1) * NOUT + oidx];
            float w2 = rootm[(kk + 2) * NOUT + oidx];
            float w3 = rootm[(kk + 3) * NOUT + oidx];
            #pragma unroll
            for (int g = 0; g < 8; ++g) {
                float4 s4 = *(const float4*)&slds[g][512 + kk];
                acc[g] = fmaf(s4.x, w0, acc[g]);
                acc[g] = fmaf(s4.y, w1, acc[g]);
                acc[g] = fmaf(s4.z, w2, acc[g]);
                acc[g] = fmaf(s4.w, w3, acc[g]);
            }
        }
    }
    #pragma unroll
    for (int g = 0; g < 8; ++g) pl[r][g][f] = acc[g];
    __syncthreads();

    // ---- Reduce partials + bias (+ReLU), store ----
    {
        int g = tid >> 6;       // one node per wave
        float sum = bias[oidx];
        #pragma unroll
        for (int w = 0; w < 8; ++w) sum += pl[w][g][f];
        if (RELU) sum = fmaxf(sum, 0.0f);
        if (f < NOUT) out[(node0 + g) * NOUT + f] = sum;
    }
}

// ---------------------------------------------------------------------------
// Launch
// ---------------------------------------------------------------------------
extern "C" void kernel_launch(void* const* d_in, const int* in_sizes, int n_in,
                              void* d_out, int out_size, void* d_ws, size_t ws_size,
                              hipStream_t stream) {
    const float* x     = (const float*)d_in[0];
    const int*   ei    = (const int*)d_in[1];
    const int*   et    = (const int*)d_in[2];
    const float* W1    = (const float*)d_in[3];
    const float* root1 = (const float*)d_in[4];
    const float* b1    = (const float*)d_in[5];
    const float* W2    = (const float*)d_in[6];
    const float* root2 = (const float*)d_in[7];
    const float* b2    = (const float*)d_in[8];
    float* out = (float*)d_out;

    const int* src = ei;            // edge_index[0]
    const int* dst = ei + N_EDGES;  // edge_index[1]

    // Workspace layout (~41.7 MB total)
    char* ws = (char*)d_ws;
    int* cnt    = (int*)(ws);                                   // NSEG ints
    int* cursor = (int*)(ws + (size_t)NSEG * 4);                // NSEG ints
    int* offs   = (int*)(ws + (size_t)NSEG * 8);                // NSEG ints
    int* bsums  = (int*)(ws + (size_t)NSEG * 12);               // 1024 ints
    int* ssrc   = (int*)(ws + (size_t)NSEG * 12 + 4096);        // N_EDGES ints
    float* h1   = (float*)(ws + (size_t)NSEG * 12 + 4096 + (size_t)N_EDGES * 4); // N*64 floats

    // zero cnt + cursor (adjacent)
    hipMemsetAsync(ws, 0, (size_t)NSEG * 8, stream);

    int eb = (N_EDGES + 255) / 256;
    k_hist<<<eb, 256, 0, stream>>>(dst, et, cnt);
    k_scanA<<<SCAN_NB, 256, 0, stream>>>(cnt, bsums);
    k_scanB<<<1, 1024, 0, stream>>>(bsums);
    k_scanC<<<SCAN_NB, 256, 0, stream>>>(cnt, bsums, offs);
    k_scatter<<<eb, 256, 0, stream>>>(src, dst, et, offs, cursor, ssrc);

    // Layer 1: x -> h1 (ReLU), NOUT=64
    k_layer<64, true><<<N_NODES / 8, 512, 0, stream>>>(x, offs, cnt, ssrc, W1, root1, b1, h1);
    // Layer 2: h1 -> out, NOUT=32
    k_layer<32, false><<<N_NODES / 8, 512, 0, stream>>>(h1, offs, cnt, ssrc, W2, root2, b2, out);
}

// Round 2
// 798.014 us; speedup vs baseline: 1.5916x; 1.5916x over previous
//
#include <hip/hip_runtime.h>
#include <hip/hip_bf16.h>

// Problem constants (from reference)
#define N_NODES 100000
#define N_EDGES 1600000
#define N_RELS  8
#define IN_F    64
#define HID_F   64
#define OUT_F   32
#define NSEG    (N_NODES * N_RELS)      // 800000 (node, rel) segments
#define SCAN_EPB 1024                   // elements per scan block (256 thr x 4)
#define SCAN_NB  ((NSEG + SCAN_EPB - 1) / SCAN_EPB)  // 782

// ---------------------------------------------------------------------------
// 1) Histogram: cnt[dst*8+etype] += 1
// ---------------------------------------------------------------------------
__global__ void k_hist(const int* __restrict__ dst, const int* __restrict__ et,
                       int* __restrict__ cnt) {
    int e = blockIdx.x * blockDim.x + threadIdx.x;
    if (e < N_EDGES) {
        int seg = dst[e] * N_RELS + et[e];
        atomicAdd(&cnt[seg], 1);
    }
}

// ---------------------------------------------------------------------------
// 2a) Scan pass A: per-block sums (1024 elems / block, 256 threads x 4)
// ---------------------------------------------------------------------------
__global__ void k_scanA(const int* __restrict__ cnt, int* __restrict__ bsums) {
    __shared__ int red[256];
    int t = threadIdx.x;
    int base = blockIdx.x * SCAN_EPB + t * 4;
    int s = 0;
    #pragma unroll
    for (int j = 0; j < 4; ++j) {
        int idx = base + j;
        if (idx < NSEG) s += cnt[idx];
    }
    red[t] = s;
    __syncthreads();
    for (int st = 128; st > 0; st >>= 1) {
        if (t < st) red[t] += red[t + st];
        __syncthreads();
    }
    if (t == 0) bsums[blockIdx.x] = red[0];
}

// ---------------------------------------------------------------------------
// 2b) Scan pass B: exclusive scan of block sums (NB=782 <= 1024), one block
// ---------------------------------------------------------------------------
__global__ void k_scanB(int* __restrict__ bsums) {
    __shared__ int s[1024];
    int t = threadIdx.x;
    int own = (t < SCAN_NB) ? bsums[t] : 0;
    s[t] = own;
    __syncthreads();
    for (int off = 1; off < 1024; off <<= 1) {
        int v = (t >= off) ? s[t - off] : 0;
        __syncthreads();
        s[t] += v;
        __syncthreads();
    }
    if (t < SCAN_NB) bsums[t] = s[t] - own;   // exclusive
}

// ---------------------------------------------------------------------------
// 2c) Scan pass C: per-element exclusive offsets = blockBase + local prefix
// ---------------------------------------------------------------------------
__global__ void k_scanC(const int* __restrict__ cnt, const int* __restrict__ bsums,
                        int* __restrict__ offs) {
    __shared__ int ts[256];
    int t = threadIdx.x;
    int base = blockIdx.x * SCAN_EPB + t * 4;
    int v[4];
    int local = 0;
    #pragma unroll
    for (int j = 0; j < 4; ++j) {
        int idx = base + j;
        v[j] = (idx < NSEG) ? cnt[idx] : 0;
        local += v[j];
    }
    ts[t] = local;
    __syncthreads();
    for (int off = 1; off < 256; off <<= 1) {
        int x = (t >= off) ? ts[t - off] : 0;
        __syncthreads();
        ts[t] += x;
        __syncthreads();
    }
    int run = bsums[blockIdx.x] + (ts[t] - local);  // exclusive start for this thread
    #pragma unroll
    for (int j = 0; j < 4; ++j) {
        int idx = base + j;
        if (idx < NSEG) offs[idx] = run;
        run += v[j];
    }
}

// ---------------------------------------------------------------------------
// 3) Scatter edges into seg-sorted order, PACKED: val = src*16 + rel
//    (src < 100000 -> fits easily; rel in [0,8); pad value 15 decodes to
//     rel=15 (matches no accumulator) and src=0 (safe gather))
// ---------------------------------------------------------------------------
__global__ void k_scatter(const int* __restrict__ src, const int* __restrict__ dst,
                          const int* __restrict__ et, const int* __restrict__ offs,
                          int* __restrict__ cursor, int* __restrict__ ssrc) {
    int e = blockIdx.x * blockDim.x + threadIdx.x;
    if (e < N_EDGES) {
        int r = et[e];
        int seg = dst[e] * N_RELS + r;
        int pos = offs[seg] + atomicAdd(&cursor[seg], 1);
        ssrc[pos] = src[e] * 16 + r;
    }
}

// ---------------------------------------------------------------------------
// 4) Fused layer: per-(node,rel) mean aggregation + [576]x[576,NOUT] GEMV
//    Block = 512 threads handles 8 nodes.
//    Phase 1: wave w owns node w. All edges of a node are CONTIGUOUS in ssrc
//             (seg-sorted). Lanes vector-load the packed edge list, broadcast
//             via shfl, issue 8 independent gathers per step, accumulate into
//             8 per-rel register accumulators (branchless). No serial
//             dependent-load chain.
//    Phase 2: wave w handles k-chunk [w*64, w*64+64) for all 8 nodes (weights
//             stay in registers, reused across nodes -> 1 pass of W per
//             block); wave 0 also does the root chunk. Partials to LDS pl,
//             then reduce + bias(+ReLU).
// ---------------------------------------------------------------------------
template <int NOUT, bool RELU>
__global__ __launch_bounds__(512) void k_layer(
        const float* __restrict__ xin, const int* __restrict__ offs,
        const int* __restrict__ cnt, const int* __restrict__ ssrc,
        const float* __restrict__ Wm, const float* __restrict__ rootm,
        const float* __restrict__ bias, float* __restrict__ out) {
    __shared__ float slds[8][576];
    __shared__ float pl[8][8][64];   // [wave][node g][o]

    const int tid = threadIdx.x;
    const int w = tid >> 6;          // wave index
    const int f = tid & 63;          // lane == feature / output col
    const int node0 = blockIdx.x * 8;
    const int node = node0 + w;      // this wave's node in phase 1

    // ---- Phase 1 metadata: lanes 0..7 load offs/cnt for the 8 rels ----
    int ov = 0, cv = 0;
    if (f < 8) {
        ov = offs[node * N_RELS + f];
        cv = cnt[node * N_RELS + f];
    }
    const int s0 = __shfl(ov, 0);
    const int ct = __shfl(ov, 7) + __shfl(cv, 7) - s0;   // total edges of node

    // stage own node's x row for the root term (independent load)
    slds[w][512 + f] = xin[node * 64 + f];

    float a[8];
    #pragma unroll
    for (int r = 0; r < 8; ++r) a[r] = 0.0f;

    // ---- Phase 1: chunked, latency-parallel edge aggregation ----
    for (int cb = 0; cb < ct; cb += 64) {
        int n = ct - cb;
        if (n > 64) n = 64;
        int pk = 15;                          // pad: rel=15, src=0
        if (f < n) pk = ssrc[s0 + cb + f];    // coalesced vector load
        int nn = (n + 7) & ~7;
        for (int e = 0; e < nn; e += 8) {
            int p[8];
            float xv[8];
            #pragma unroll
            for (int i = 0; i < 8; ++i) p[i] = __shfl(pk, e + i);
            #pragma unroll
            for (int i = 0; i < 8; ++i) xv[i] = xin[(p[i] >> 4) * 64 + f]; // 8 indep gathers
            #pragma unroll
            for (int i = 0; i < 8; ++i) {
                int rl = p[i] & 15;
                #pragma unroll
                for (int r = 0; r < 8; ++r)
                    a[r] += (rl == r) ? xv[i] : 0.0f;
            }
        }
    }

    // normalize and write to LDS
    #pragma unroll
    for (int r = 0; r < 8; ++r) {
        int c = __shfl(cv, r);
        slds[w][r * 64 + f] = a[r] * (1.0f / (float)(c > 0 ? c : 1));
    }
    __syncthreads();

    // ---- Phase 2: GEMV, k-partitioned across the 8 waves ----
    const int oidx = (f < NOUT) ? f : 0;   // safe weight column
    float acc[8];
    #pragma unroll
    for (int g = 0; g < 8; ++g) acc[g] = 0.0f;

    const int kb = w * 64;
    #pragma unroll 4
    for (int kk = 0; kk < 64; kk += 4) {
        int k = kb + kk;
        float w0 = Wm[(k + 0) * NOUT + oidx];
        float w1 = Wm[(k + 1) * NOUT + oidx];
        float w2 = Wm[(k + 2) * NOUT + oidx];
        float w3 = Wm[(k + 3) * NOUT + oidx];
        #pragma unroll
        for (int g = 0; g < 8; ++g) {
            float4 s4 = *(const float4*)&slds[g][k];
            acc[g] = fmaf(s4.x, w0, acc[g]);
            acc[g] = fmaf(s4.y, w1, acc[g]);
            acc[g] = fmaf(s4.z, w2, acc[g]);
            acc[g] = fmaf(s4.w, w3, acc[g]);
        }
    }
    if (w == 0) {  // root chunk k in [512, 576)
        #pragma unroll 4
        for (int kk = 0; kk < 64; kk += 4) {
            float w0 = rootm[(kk + 0) * NOUT + oidx];
            float w1 = rootm[(kk + 1) * NOUT + oidx];
            float w2 = rootm[(kk + 2) * NOUT + oidx];
            float w3 = rootm[(kk + 3) * NOUT + oidx];
            #pragma unroll
            for (int g = 0; g < 8; ++g) {
                float4 s4 = *(const float4*)&slds[g][512 + kk];
                acc[g] = fmaf(s4.x, w0, acc[g]);
                acc[g] = fmaf(s4.y, w1, acc[g]);
                acc[g] = fmaf(s4.z, w2, acc[g]);
                acc[g] = fmaf(s4.w, w3, acc[g]);
            }
        }
    }
    #pragma unroll
    for (int g = 0; g < 8; ++g) pl[w][g][f] = acc[g];
    __syncthreads();

    // ---- Reduce partials + bias (+ReLU), store ----
    {
        int g = tid >> 6;       // one node per wave
        float sum = bias[oidx];
        #pragma unroll
        for (int v = 0; v < 8; ++v) sum += pl[v][g][f];
        if (RELU) sum = fmaxf(sum, 0.0f);
        if (f < NOUT) out[(node0 + g) * NOUT + f] = sum;
    }
}

// ---------------------------------------------------------------------------
// Launch
// ---------------------------------------------------------------------------
extern "C" void kernel_launch(void* const* d_in, const int* in_sizes, int n_in,
                              void* d_out, int out_size, void* d_ws, size_t ws_size,
                              hipStream_t stream) {
    const float* x     = (const float*)d_in[0];
    const int*   ei    = (const int*)d_in[1];
    const int*   et    = (const int*)d_in[2];
    const float* W1    = (const float*)d_in[3];
    const float* root1 = (const float*)d_in[4];
    const float* b1    = (const float*)d_in[5];
    const float* W2    = (const float*)d_in[6];
    const float* root2 = (const float*)d_in[7];
    const float* b2    = (const float*)d_in[8];
    float* out = (float*)d_out;

    const int* src = ei;            // edge_index[0]
    const int* dst = ei + N_EDGES;  // edge_index[1]

    // Workspace layout (~41.7 MB total)
    char* ws = (char*)d_ws;
    int* cnt    = (int*)(ws);                                   // NSEG ints
    int* cursor = (int*)(ws + (size_t)NSEG * 4);                // NSEG ints
    int* offs   = (int*)(ws + (size_t)NSEG * 8);                // NSEG ints
    int* bsums  = (int*)(ws + (size_t)NSEG * 12);               // 1024 ints
    int* ssrc   = (int*)(ws + (size_t)NSEG * 12 + 4096);        // N_EDGES ints
    float* h1   = (float*)(ws + (size_t)NSEG * 12 + 4096 + (size_t)N_EDGES * 4); // N*64 floats

    // zero cnt + cursor (adjacent)
    hipMemsetAsync(ws, 0, (size_t)NSEG * 8, stream);

    int eb = (N_EDGES + 255) / 256;
    k_hist<<<eb, 256, 0, stream>>>(dst, et, cnt);
    k_scanA<<<SCAN_NB, 256, 0, stream>>>(cnt, bsums);
    k_scanB<<<1, 1024, 0, stream>>>(bsums);
    k_scanC<<<SCAN_NB, 256, 0, stream>>>(cnt, bsums, offs);
    k_scatter<<<eb, 256, 0, stream>>>(src, dst, et, offs, cursor, ssrc);

    // Layer 1: x -> h1 (ReLU), NOUT=64
    k_layer<64, true><<<N_NODES / 8, 512, 0, stream>>>(x, offs, cnt, ssrc, W1, root1, b1, h1);
    // Layer 2: h1 -> out, NOUT=32
    k_layer<32, false><<<N_NODES / 8, 512, 0, stream>>>(h1, offs, cnt, ssrc, W2, root2, b2, out);
}

// Round 3
// 763.756 us; speedup vs baseline: 1.6630x; 1.0449x over previous
//
#include <hip/hip_runtime.h>
#include <hip/hip_bf16.h>

// Problem constants (from reference)
#define N_NODES 100000
#define N_EDGES 1600000
#define N_RELS  8
#define IN_F    64
#define HID_F   64
#define OUT_F   32
#define NSEG    (N_NODES * N_RELS)      // 800000 (node, rel) segments
#define SCAN_EPB 1024                   // elements per scan block (256 thr x 4)
#define SCAN_NB  ((NSEG + SCAN_EPB - 1) / SCAN_EPB)  // 782

// ---------------------------------------------------------------------------
// 1) Histogram: cnt[dst*8+etype] += 1
// ---------------------------------------------------------------------------
__global__ void k_hist(const int* __restrict__ dst, const int* __restrict__ et,
                       int* __restrict__ cnt) {
    int e = blockIdx.x * blockDim.x + threadIdx.x;
    if (e < N_EDGES) {
        int seg = dst[e] * N_RELS + et[e];
        atomicAdd(&cnt[seg], 1);
    }
}

// ---------------------------------------------------------------------------
// 2a) Scan pass A: per-block sums (1024 elems / block, 256 threads x 4)
// ---------------------------------------------------------------------------
__global__ void k_scanA(const int* __restrict__ cnt, int* __restrict__ bsums) {
    __shared__ int red[256];
    int t = threadIdx.x;
    int base = blockIdx.x * SCAN_EPB + t * 4;
    int s = 0;
    #pragma unroll
    for (int j = 0; j < 4; ++j) {
        int idx = base + j;
        if (idx < NSEG) s += cnt[idx];
    }
    red[t] = s;
    __syncthreads();
    for (int st = 128; st > 0; st >>= 1) {
        if (t < st) red[t] += red[t + st];
        __syncthreads();
    }
    if (t == 0) bsums[blockIdx.x] = red[0];
}

// ---------------------------------------------------------------------------
// 2b) Scan pass B: exclusive scan of block sums (NB=782 <= 1024), one block
// ---------------------------------------------------------------------------
__global__ void k_scanB(int* __restrict__ bsums) {
    __shared__ int s[1024];
    int t = threadIdx.x;
    int own = (t < SCAN_NB) ? bsums[t] : 0;
    s[t] = own;
    __syncthreads();
    for (int off = 1; off < 1024; off <<= 1) {
        int v = (t >= off) ? s[t - off] : 0;
        __syncthreads();
        s[t] += v;
        __syncthreads();
    }
    if (t < SCAN_NB) bsums[t] = s[t] - own;   // exclusive
}

// ---------------------------------------------------------------------------
// 2c) Scan pass C: per-element exclusive offsets = blockBase + local prefix
// ---------------------------------------------------------------------------
__global__ void k_scanC(const int* __restrict__ cnt, const int* __restrict__ bsums,
                        int* __restrict__ offs) {
    __shared__ int ts[256];
    int t = threadIdx.x;
    int base = blockIdx.x * SCAN_EPB + t * 4;
    int v[4];
    int local = 0;
    #pragma unroll
    for (int j = 0; j < 4; ++j) {
        int idx = base + j;
        v[j] = (idx < NSEG) ? cnt[idx] : 0;
        local += v[j];
    }
    ts[t] = local;
    __syncthreads();
    for (int off = 1; off < 256; off <<= 1) {
        int x = (t >= off) ? ts[t - off] : 0;
        __syncthreads();
        ts[t] += x;
        __syncthreads();
    }
    int run = bsums[blockIdx.x] + (ts[t] - local);  // exclusive start for this thread
    #pragma unroll
    for (int j = 0; j < 4; ++j) {
        int idx = base + j;
        if (idx < NSEG) offs[idx] = run;
        run += v[j];
    }
}

// ---------------------------------------------------------------------------
// 3) Scatter edges into seg-sorted order (plain src; rel implied by segment)
// ---------------------------------------------------------------------------
__global__ void k_scatter(const int* __restrict__ src, const int* __restrict__ dst,
                          const int* __restrict__ et, const int* __restrict__ offs,
                          int* __restrict__ cursor, int* __restrict__ ssrc) {
    int e = blockIdx.x * blockDim.x + threadIdx.x;
    if (e < N_EDGES) {
        int seg = dst[e] * N_RELS + et[e];
        int pos = offs[seg] + atomicAdd(&cursor[seg], 1);
        ssrc[pos] = src[e];
    }
}

// ---------------------------------------------------------------------------
// 3b) Weight transpose: Wt[o][k] (k in [0,576); last 64 = root rows)
//     Lets phase 2 load weights as float4 along k.
// ---------------------------------------------------------------------------
__global__ void k_wt(const float* __restrict__ W, const float* __restrict__ root,
                     float* __restrict__ Wt, int nout) {
    int idx = blockIdx.x * 256 + threadIdx.x;
    if (idx >= 576 * nout) return;
    int o = idx / 576;
    int k = idx - o * 576;
    float v = (k < 512) ? W[k * nout + o] : root[(k - 512) * nout + o];
    Wt[o * 576 + k] = v;
}

// ---------------------------------------------------------------------------
// 4) Fused layer. Block = 512 threads = 8 waves, 8 nodes.
//    Phase 1: wave w owns node w. Edges are rel-sorted and contiguous per
//             node. For each rel (COMPILE-TIME unrolled -> static accumulator,
//             zero select VALU), broadcast src via readlane (SGPR -> s-base
//             gather, ~2 VALU/edge), batches of 4 for latency parallelism.
//    Phase 2: wave w handles k-chunk [w*72, w*72+72) of the [8x576]x[576xNOUT]
//             GEMM with float4 weight loads from Wt (root folded in, no
//             special case). Partials to LDS pl, reduce + bias(+ReLU).
// ---------------------------------------------------------------------------
template <int NOUT, bool RELU>
__global__ __launch_bounds__(512) void k_layer(
        const float* __restrict__ xin, const int* __restrict__ offs,
        const int* __restrict__ cnt, const int* __restrict__ ssrc,
        const float* __restrict__ Wt, const float* __restrict__ bias,
        float* __restrict__ out) {
    __shared__ float slds[8][576];
    __shared__ float pl[8][8][64];   // [wave][node g][o]

    const int tid = threadIdx.x;
    const int w = tid >> 6;          // wave index
    const int f = tid & 63;          // lane == feature / output col
    const int node0 = blockIdx.x * 8;
    const int node = node0 + w;      // this wave's node in phase 1

    // ---- Phase 1 metadata: lanes 0..7 load offs/cnt for the 8 rels ----
    int ov = 0, cv = 0;
    if (f < 8) {
        ov = offs[node * N_RELS + f];
        cv = cnt[node * N_RELS + f];
    }
    int sr[8], cr[8];
    #pragma unroll
    for (int r = 0; r < 8; ++r) {
        sr[r] = __builtin_amdgcn_readlane(ov, r);   // SGPR
        cr[r] = __builtin_amdgcn_readlane(cv, r);   // SGPR
    }
    // vector-load each rel's edge list chunk (independent, issue up front)
    int pk[8];
    #pragma unroll
    for (int r = 0; r < 8; ++r)
        pk[r] = (f < cr[r]) ? ssrc[sr[r] + f] : 0;

    // stage own node's x row for the root term
    slds[w][512 + f] = xin[node * 64 + f];

    const float* __restrict__ xf = xin + f;

    #pragma unroll
    for (int r = 0; r < 8; ++r) {
        float ar = 0.0f;
        const int c = cr[r];
        const int cc = c < 64 ? c : 64;
        int e = 0;
        for (; e + 4 <= cc; e += 4) {            // 4 independent gathers/step
            int i0 = __builtin_amdgcn_readlane(pk[r], e + 0);
            int i1 = __builtin_amdgcn_readlane(pk[r], e + 1);
            int i2 = __builtin_amdgcn_readlane(pk[r], e + 2);
            int i3 = __builtin_amdgcn_readlane(pk[r], e + 3);
            float v0 = xf[(size_t)i0 * 64];
            float v1 = xf[(size_t)i1 * 64];
            float v2 = xf[(size_t)i2 * 64];
            float v3 = xf[(size_t)i3 * 64];
            ar += (v0 + v1) + (v2 + v3);
        }
        for (; e < cc; ++e) {                    // 0-3 remainder
            int i0 = __builtin_amdgcn_readlane(pk[r], e);
            ar += xf[(size_t)i0 * 64];
        }
        for (; e < c; ++e) {                     // rare: degree > 64 fallback
            ar += xf[(size_t)ssrc[sr[r] + e] * 64];
        }
        float inv = 1.0f / (float)(c > 0 ? c : 1);
        slds[w][r * 64 + f] = ar * inv;
    }
    __syncthreads();

    // ---- Phase 2: GEMM k-partitioned across the 8 waves (72 k each) ----
    const int oidx = (f < NOUT) ? f : 0;   // safe weight row
    float acc[8];
    #pragma unroll
    for (int g = 0; g < 8; ++g) acc[g] = 0.0f;

    const int kb = w * 72;
    const float* __restrict__ wrow = Wt + oidx * 576 + kb;
    #pragma unroll
    for (int kk = 0; kk < 72; kk += 4) {
        float4 wv = *(const float4*)&wrow[kk];
        #pragma unroll
        for (int g = 0; g < 8; ++g) {
            float4 s4 = *(const float4*)&slds[g][kb + kk];
            acc[g] = fmaf(s4.x, wv.x, acc[g]);
            acc[g] = fmaf(s4.y, wv.y, acc[g]);
            acc[g] = fmaf(s4.z, wv.z, acc[g]);
            acc[g] = fmaf(s4.w, wv.w, acc[g]);
        }
    }
    #pragma unroll
    for (int g = 0; g < 8; ++g) pl[w][g][f] = acc[g];
    __syncthreads();

    // ---- Reduce partials + bias (+ReLU), store ----
    {
        int g = tid >> 6;       // one node per wave
        float sum = bias[oidx];
        #pragma unroll
        for (int v = 0; v < 8; ++v) sum += pl[v][g][f];
        if (RELU) sum = fmaxf(sum, 0.0f);
        if (f < NOUT) out[(node0 + g) * NOUT + f] = sum;
    }
}

// ---------------------------------------------------------------------------
// Launch
// ---------------------------------------------------------------------------
extern "C" void kernel_launch(void* const* d_in, const int* in_sizes, int n_in,
                              void* d_out, int out_size, void* d_ws, size_t ws_size,
                              hipStream_t stream) {
    const float* x     = (const float*)d_in[0];
    const int*   ei    = (const int*)d_in[1];
    const int*   et    = (const int*)d_in[2];
    const float* W1    = (const float*)d_in[3];
    const float* root1 = (const float*)d_in[4];
    const float* b1    = (const float*)d_in[5];
    const float* W2    = (const float*)d_in[6];
    const float* root2 = (const float*)d_in[7];
    const float* b2    = (const float*)d_in[8];
    float* out = (float*)d_out;

    const int* src = ei;            // edge_index[0]
    const int* dst = ei + N_EDGES;  // edge_index[1]

    // Workspace layout (~41.7 MB total; Wt1/Wt2 reuse the cursor region,
    // which is dead after k_scatter and re-zeroed by the memset each launch)
    char* ws = (char*)d_ws;
    int* cnt    = (int*)(ws);                                   // NSEG ints
    int* cursor = (int*)(ws + (size_t)NSEG * 4);                // NSEG ints
    int* offs   = (int*)(ws + (size_t)NSEG * 8);                // NSEG ints
    int* bsums  = (int*)(ws + (size_t)NSEG * 12);               // 1024 ints
    int* ssrc   = (int*)(ws + (size_t)NSEG * 12 + 4096);        // N_EDGES ints
    float* h1   = (float*)(ws + (size_t)NSEG * 12 + 4096 + (size_t)N_EDGES * 4); // N*64 floats
    float* Wt1  = (float*)cursor;                               // 64*576 floats (147KB)
    float* Wt2  = (float*)(ws + (size_t)NSEG * 4 + 64 * 576 * 4); // 32*576 floats

    // zero cnt + cursor (adjacent)
    hipMemsetAsync(ws, 0, (size_t)NSEG * 8, stream);

    int eb = (N_EDGES + 255) / 256;
    k_hist<<<eb, 256, 0, stream>>>(dst, et, cnt);
    k_scanA<<<SCAN_NB, 256, 0, stream>>>(cnt, bsums);
    k_scanB<<<1, 1024, 0, stream>>>(bsums);
    k_scanC<<<SCAN_NB, 256, 0, stream>>>(cnt, bsums, offs);
    k_scatter<<<eb, 256, 0, stream>>>(src, dst, et, offs, cursor, ssrc);

    // cursor is dead now; build transposed weights in its place
    k_wt<<<(576 * 64 + 255) / 256, 256, 0, stream>>>(W1, root1, Wt1, 64);
    k_wt<<<(576 * 32 + 255) / 256, 256, 0, stream>>>(W2, root2, Wt2, 32);

    // Layer 1: x -> h1 (ReLU), NOUT=64
    k_layer<64, true><<<N_NODES / 8, 512, 0, stream>>>(x, offs, cnt, ssrc, Wt1, b1, h1);
    // Layer 2: h1 -> out, NOUT=32
    k_layer<32, false><<<N_NODES / 8, 512, 0, stream>>>(h1, offs, cnt, ssrc, Wt2, b2, out);
}

// Round 4
// 728.300 us; speedup vs baseline: 1.7439x; 1.0487x over previous
//
#include <hip/hip_runtime.h>
#include <hip/hip_bf16.h>

// Problem constants (from reference)
#define N_NODES 100000
#define N_EDGES 1600000
#define N_RELS  8
#define IN_F    64
#define HID_F   64
#define OUT_F   32
#define NSEG    (N_NODES * N_RELS)      // 800000 (node, rel) segments
#define SCAN_EPB 1024                   // elements per scan block (256 thr x 4)
#define SCAN_NB  ((NSEG + SCAN_EPB - 1) / SCAN_EPB)  // 782

// ---------------------------------------------------------------------------
// 1) Histogram: cnt[dst*8+etype] += 1
// ---------------------------------------------------------------------------
__global__ void k_hist(const int* __restrict__ dst, const int* __restrict__ et,
                       int* __restrict__ cnt) {
    int e = blockIdx.x * blockDim.x + threadIdx.x;
    if (e < N_EDGES) {
        int seg = dst[e] * N_RELS + et[e];
        atomicAdd(&cnt[seg], 1);
    }
}

// ---------------------------------------------------------------------------
// 2a) Scan pass A: per-block sums (1024 elems / block, 256 threads x 4)
// ---------------------------------------------------------------------------
__global__ void k_scanA(const int* __restrict__ cnt, int* __restrict__ bsums) {
    __shared__ int red[256];
    int t = threadIdx.x;
    int base = blockIdx.x * SCAN_EPB + t * 4;
    int s = 0;
    #pragma unroll
    for (int j = 0; j < 4; ++j) {
        int idx = base + j;
        if (idx < NSEG) s += cnt[idx];
    }
    red[t] = s;
    __syncthreads();
    for (int st = 128; st > 0; st >>= 1) {
        if (t < st) red[t] += red[t + st];
        __syncthreads();
    }
    if (t == 0) bsums[blockIdx.x] = red[0];
}

// ---------------------------------------------------------------------------
// 2b) Scan pass B: exclusive scan of block sums (NB=782 <= 1024), one block
// ---------------------------------------------------------------------------
__global__ void k_scanB(int* __restrict__ bsums) {
    __shared__ int s[1024];
    int t = threadIdx.x;
    int own = (t < SCAN_NB) ? bsums[t] : 0;
    s[t] = own;
    __syncthreads();
    for (int off = 1; off < 1024; off <<= 1) {
        int v = (t >= off) ? s[t - off] : 0;
        __syncthreads();
        s[t] += v;
        __syncthreads();
    }
    if (t < SCAN_NB) bsums[t] = s[t] - own;   // exclusive
}

// ---------------------------------------------------------------------------
// 2c) Scan pass C: per-element exclusive offsets = blockBase + local prefix
// ---------------------------------------------------------------------------
__global__ void k_scanC(const int* __restrict__ cnt, const int* __restrict__ bsums,
                        int* __restrict__ offs) {
    __shared__ int ts[256];
    int t = threadIdx.x;
    int base = blockIdx.x * SCAN_EPB + t * 4;
    int v[4];
    int local = 0;
    #pragma unroll
    for (int j = 0; j < 4; ++j) {
        int idx = base + j;
        v[j] = (idx < NSEG) ? cnt[idx] : 0;
        local += v[j];
    }
    ts[t] = local;
    __syncthreads();
    for (int off = 1; off < 256; off <<= 1) {
        int x = (t >= off) ? ts[t - off] : 0;
        __syncthreads();
        ts[t] += x;
        __syncthreads();
    }
    int run = bsums[blockIdx.x] + (ts[t] - local);  // exclusive start for this thread
    #pragma unroll
    for (int j = 0; j < 4; ++j) {
        int idx = base + j;
        if (idx < NSEG) offs[idx] = run;
        run += v[j];
    }
}

// ---------------------------------------------------------------------------
// 3) Scatter edges into seg-sorted order, PACKED: val = src*16 + rel
//    (pad value 15 decodes to rel=15 -> routes to no accumulator, src=0 safe)
// ---------------------------------------------------------------------------
__global__ void k_scatter(const int* __restrict__ src, const int* __restrict__ dst,
                          const int* __restrict__ et, const int* __restrict__ offs,
                          int* __restrict__ cursor, int* __restrict__ ssrc) {
    int e = blockIdx.x * blockDim.x + threadIdx.x;
    if (e < N_EDGES) {
        int r = et[e];
        int seg = dst[e] * N_RELS + r;
        int pos = offs[seg] + atomicAdd(&cursor[seg], 1);
        ssrc[pos] = src[e] * 16 + r;
    }
}

// ---------------------------------------------------------------------------
// 3b) Weight transpose: Wt[o][k] (k in [0,576); last 64 = root rows)
// ---------------------------------------------------------------------------
__global__ void k_wt(const float* __restrict__ W, const float* __restrict__ root,
                     float* __restrict__ Wt, int nout) {
    int idx = blockIdx.x * 256 + threadIdx.x;
    if (idx >= 576 * nout) return;
    int o = idx / 576;
    int k = idx - o * 576;
    float v = (k < 512) ? W[k * nout + o] : root[(k - 512) * nout + o];
    Wt[o * 576 + k] = v;
}

// ---------------------------------------------------------------------------
// 4) Fused layer. Block = 512 threads = 8 waves, 8 nodes.
//    Phase 1: wave w owns node w. Flat edge loop in groups of 16:
//             16 readlane broadcasts (SGPR), 16 INDEPENDENT gathers issued
//             before any use (one latency exposure per group), then routing
//             via wave-uniform scalar if-tree (1 v_add/edge). Combines R2's
//             latency parallelism with ~2 VALU/edge routing.
//    Phase 2: wave w handles k-chunk [w*72, w*72+72) of [8x576]x[576xNOUT]
//             GEMM, float4 weight loads from Wt (root folded in).
//    Phase 3: reduce partials + bias (+ReLU).
// ---------------------------------------------------------------------------
template <int NOUT, bool RELU>
__global__ __launch_bounds__(512) void k_layer(
        const float* __restrict__ xin, const int* __restrict__ offs,
        const int* __restrict__ cnt, const int* __restrict__ ssrc,
        const float* __restrict__ Wt, const float* __restrict__ bias,
        float* __restrict__ out) {
    __shared__ float slds[8][576];
    __shared__ float pl[8][8][64];   // [wave][node g][o]

    const int tid = threadIdx.x;
    const int w = tid >> 6;          // wave index
    const int f = tid & 63;          // lane == feature / output col
    const int node0 = blockIdx.x * 8;
    const int node = node0 + w;      // this wave's node in phase 1

    // ---- Phase 1 metadata: lanes 0..7 load offs/cnt for the 8 rels ----
    int ov = 0, cv = 0;
    if (f < 8) {
        ov = offs[node * N_RELS + f];
        cv = cnt[node * N_RELS + f];
    }
    const int s0 = __builtin_amdgcn_readlane(ov, 0);
    const int ct = __builtin_amdgcn_readlane(ov, 7)
                 + __builtin_amdgcn_readlane(cv, 7) - s0;   // total edges (scalar)

    // stage own node's x row for the root term (independent load)
    slds[w][512 + f] = xin[node * 64 + f];

    const float* __restrict__ xf = xin + f;

    float a[8];
    #pragma unroll
    for (int r = 0; r < 8; ++r) a[r] = 0.0f;

    // ---- Phase 1: flat edge loop, 16 gathers in flight per group ----
    for (int cb = 0; cb < ct; cb += 64) {
        int n = ct - cb;
        if (n > 64) n = 64;
        int pk = 15;                          // pad: rel=15, src=0
        if (f < n) pk = ssrc[s0 + cb + f];    // coalesced vector load
        for (int e = 0; e < n; e += 16) {
            int pv[16];
            float xv[16];
            #pragma unroll
            for (int i = 0; i < 16; ++i)
                pv[i] = __builtin_amdgcn_readlane(pk, e + i);   // SGPR
            #pragma unroll
            for (int i = 0; i < 16; ++i)
                xv[i] = xf[(size_t)(pv[i] >> 4) * 64];          // 16 indep gathers
            #pragma unroll
            for (int i = 0; i < 16; ++i) {
                const int rl = pv[i] & 15;                      // scalar
                if (rl < 4) {
                    if (rl < 2) { if (rl == 0) a[0] += xv[i]; else a[1] += xv[i]; }
                    else        { if (rl == 2) a[2] += xv[i]; else a[3] += xv[i]; }
                } else if (rl < 8) {
                    if (rl < 6) { if (rl == 4) a[4] += xv[i]; else a[5] += xv[i]; }
                    else        { if (rl == 6) a[6] += xv[i]; else a[7] += xv[i]; }
                }   // rl >= 8: pad, drop
            }
        }
    }

    // normalize and write to LDS
    #pragma unroll
    for (int r = 0; r < 8; ++r) {
        int c = __builtin_amdgcn_readlane(cv, r);
        slds[w][r * 64 + f] = a[r] * (1.0f / (float)(c > 0 ? c : 1));
    }
    __syncthreads();

    // ---- Phase 2: GEMM k-partitioned across the 8 waves (72 k each) ----
    const int oidx = (f < NOUT) ? f : 0;   // safe weight row
    float acc[8];
    #pragma unroll
    for (int g = 0; g < 8; ++g) acc[g] = 0.0f;

    const int kb = w * 72;
    const float* __restrict__ wrow = Wt + oidx * 576 + kb;
    #pragma unroll
    for (int kk = 0; kk < 72; kk += 4) {
        float4 wv = *(const float4*)&wrow[kk];
        #pragma unroll
        for (int g = 0; g < 8; ++g) {
            float4 s4 = *(const float4*)&slds[g][kb + kk];
            acc[g] = fmaf(s4.x, wv.x, acc[g]);
            acc[g] = fmaf(s4.y, wv.y, acc[g]);
            acc[g] = fmaf(s4.z, wv.z, acc[g]);
            acc[g] = fmaf(s4.w, wv.w, acc[g]);
        }
    }
    #pragma unroll
    for (int g = 0; g < 8; ++g) pl[w][g][f] = acc[g];
    __syncthreads();

    // ---- Reduce partials + bias (+ReLU), store ----
    {
        int g = tid >> 6;       // one node per wave
        float sum = bias[oidx];
        #pragma unroll
        for (int v = 0; v < 8; ++v) sum += pl[v][g][f];
        if (RELU) sum = fmaxf(sum, 0.0f);
        if (f < NOUT) out[(node0 + g) * NOUT + f] = sum;
    }
}

// ---------------------------------------------------------------------------
// Launch
// ---------------------------------------------------------------------------
extern "C" void kernel_launch(void* const* d_in, const int* in_sizes, int n_in,
                              void* d_out, int out_size, void* d_ws, size_t ws_size,
                              hipStream_t stream) {
    const float* x     = (const float*)d_in[0];
    const int*   ei    = (const int*)d_in[1];
    const int*   et    = (const int*)d_in[2];
    const float* W1    = (const float*)d_in[3];
    const float* root1 = (const float*)d_in[4];
    const float* b1    = (const float*)d_in[5];
    const float* W2    = (const float*)d_in[6];
    const float* root2 = (const float*)d_in[7];
    const float* b2    = (const float*)d_in[8];
    float* out = (float*)d_out;

    const int* src = ei;            // edge_index[0]
    const int* dst = ei + N_EDGES;  // edge_index[1]

    // Workspace layout (~41.7 MB total; Wt1/Wt2 reuse the cursor region,
    // which is dead after k_scatter and re-zeroed by the memset each launch)
    char* ws = (char*)d_ws;
    int* cnt    = (int*)(ws);                                   // NSEG ints
    int* cursor = (int*)(ws + (size_t)NSEG * 4);                // NSEG ints
    int* offs   = (int*)(ws + (size_t)NSEG * 8);                // NSEG ints
    int* bsums  = (int*)(ws + (size_t)NSEG * 12);               // 1024 ints
    int* ssrc   = (int*)(ws + (size_t)NSEG * 12 + 4096);        // N_EDGES ints
    float* h1   = (float*)(ws + (size_t)NSEG * 12 + 4096 + (size_t)N_EDGES * 4); // N*64 floats
    float* Wt1  = (float*)cursor;                               // 64*576 floats (147KB)
    float* Wt2  = (float*)(ws + (size_t)NSEG * 4 + 64 * 576 * 4); // 32*576 floats

    // zero cnt + cursor (adjacent)
    hipMemsetAsync(ws, 0, (size_t)NSEG * 8, stream);

    int eb = (N_EDGES + 255) / 256;
    k_hist<<<eb, 256, 0, stream>>>(dst, et, cnt);
    k_scanA<<<SCAN_NB, 256, 0, stream>>>(cnt, bsums);
    k_scanB<<<1, 1024, 0, stream>>>(bsums);
    k_scanC<<<SCAN_NB, 256, 0, stream>>>(cnt, bsums, offs);
    k_scatter<<<eb, 256, 0, stream>>>(src, dst, et, offs, cursor, ssrc);

    // cursor is dead now; build transposed weights in its place
    k_wt<<<(576 * 64 + 255) / 256, 256, 0, stream>>>(W1, root1, Wt1, 64);
    k_wt<<<(576 * 32 + 255) / 256, 256, 0, stream>>>(W2, root2, Wt2, 32);

    // Layer 1: x -> h1 (ReLU), NOUT=64
    k_layer<64, true><<<N_NODES / 8, 512, 0, stream>>>(x, offs, cnt, ssrc, Wt1, b1, h1);
    // Layer 2: h1 -> out, NOUT=32
    k_layer<32, false><<<N_NODES / 8, 512, 0, stream>>>(h1, offs, cnt, ssrc, Wt2, b2, out);
}

// Round 5
// 493.165 us; speedup vs baseline: 2.5754x; 1.4768x over previous
//
#include <hip/hip_runtime.h>
#include <hip/hip_bf16.h>

// Problem constants (from reference)
#define N_NODES 100000
#define N_EDGES 1600000
#define N_RELS  8
#define IN_F    64
#define HID_F   64
#define OUT_F   32
#define NSEG    (N_NODES * N_RELS)      // 800000 (node, rel) segments
#define SCAN_EPB 1024                   // elements per scan block (256 thr x 4)
#define SCAN_NB  ((NSEG + SCAN_EPB - 1) / SCAN_EPB)  // 782

typedef __attribute__((ext_vector_type(8))) short short8;   // 8 bf16 = 4 VGPRs
typedef __attribute__((ext_vector_type(4))) float f32x4;

__device__ __forceinline__ float b2f(unsigned short u) {
    return __uint_as_float(((unsigned)u) << 16);
}
__device__ __forceinline__ unsigned short f2b(float f) {
    unsigned u = __float_as_uint(f);
    u += 0x7FFFu + ((u >> 16) & 1u);      // RNE
    return (unsigned short)(u >> 16);
}

// ---------------------------------------------------------------------------
// 1) Histogram: cnt[dst*8+etype] += 1
// ---------------------------------------------------------------------------
__global__ void k_hist(const int* __restrict__ dst, const int* __restrict__ et,
                       int* __restrict__ cnt) {
    int e = blockIdx.x * blockDim.x + threadIdx.x;
    if (e < N_EDGES) {
        int seg = dst[e] * N_RELS + et[e];
        atomicAdd(&cnt[seg], 1);
    }
}

// ---------------------------------------------------------------------------
// 2) Three-pass exclusive scan over the 800k segment counts
// ---------------------------------------------------------------------------
__global__ void k_scanA(const int* __restrict__ cnt, int* __restrict__ bsums) {
    __shared__ int red[256];
    int t = threadIdx.x;
    int base = blockIdx.x * SCAN_EPB + t * 4;
    int s = 0;
    #pragma unroll
    for (int j = 0; j < 4; ++j) {
        int idx = base + j;
        if (idx < NSEG) s += cnt[idx];
    }
    red[t] = s;
    __syncthreads();
    for (int st = 128; st > 0; st >>= 1) {
        if (t < st) red[t] += red[t + st];
        __syncthreads();
    }
    if (t == 0) bsums[blockIdx.x] = red[0];
}

__global__ void k_scanB(int* __restrict__ bsums) {
    __shared__ int s[1024];
    int t = threadIdx.x;
    int own = (t < SCAN_NB) ? bsums[t] : 0;
    s[t] = own;
    __syncthreads();
    for (int off = 1; off < 1024; off <<= 1) {
        int v = (t >= off) ? s[t - off] : 0;
        __syncthreads();
        s[t] += v;
        __syncthreads();
    }
    if (t < SCAN_NB) bsums[t] = s[t] - own;   // exclusive
}

__global__ void k_scanC(const int* __restrict__ cnt, const int* __restrict__ bsums,
                        int* __restrict__ offs) {
    __shared__ int ts[256];
    int t = threadIdx.x;
    int base = blockIdx.x * SCAN_EPB + t * 4;
    int v[4];
    int local = 0;
    #pragma unroll
    for (int j = 0; j < 4; ++j) {
        int idx = base + j;
        v[j] = (idx < NSEG) ? cnt[idx] : 0;
        local += v[j];
    }
    ts[t] = local;
    __syncthreads();
    for (int off = 1; off < 256; off <<= 1) {
        int x = (t >= off) ? ts[t - off] : 0;
        __syncthreads();
        ts[t] += x;
        __syncthreads();
    }
    int run = bsums[blockIdx.x] + (ts[t] - local);
    #pragma unroll
    for (int j = 0; j < 4; ++j) {
        int idx = base + j;
        if (idx < NSEG) offs[idx] = run;
        run += v[j];
    }
}

// ---------------------------------------------------------------------------
// 3) Scatter edges into seg-sorted order, PACKED: val = src*16 + rel
// ---------------------------------------------------------------------------
__global__ void k_scatter(const int* __restrict__ src, const int* __restrict__ dst,
                          const int* __restrict__ et, const int* __restrict__ offs,
                          int* __restrict__ cursor, int* __restrict__ ssrc) {
    int e = blockIdx.x * blockDim.x + threadIdx.x;
    if (e < N_EDGES) {
        int r = et[e];
        int seg = dst[e] * N_RELS + r;
        int pos = offs[seg] + atomicAdd(&cursor[seg], 1);
        ssrc[pos] = src[e] * 16 + r;
    }
}

// ---------------------------------------------------------------------------
// 3b) x -> bf16 (halves gather traffic in the layer kernels)
// ---------------------------------------------------------------------------
__global__ void k_cvt(const float* __restrict__ x, ushort* __restrict__ xb) {
    int i = (blockIdx.x * 256 + threadIdx.x) * 4;
    if (i >= N_NODES * 64) return;
    float4 v = *(const float4*)(x + i);
    ushort4 u;
    u.x = f2b(v.x); u.y = f2b(v.y); u.z = f2b(v.z); u.w = f2b(v.w);
    *(ushort4*)(xb + i) = u;
}

// ---------------------------------------------------------------------------
// 3c) Weight transpose + bf16: Wtb[o][k], k in [0,576) (last 64 = root rows)
// ---------------------------------------------------------------------------
__global__ void k_wt(const float* __restrict__ W, const float* __restrict__ root,
                     ushort* __restrict__ Wtb, int nout) {
    int idx = blockIdx.x * 256 + threadIdx.x;
    if (idx >= 576 * nout) return;
    int o = idx / 576;
    int k = idx - o * 576;
    float v = (k < 512) ? W[k * nout + o] : root[(k - 512) * nout + o];
    Wtb[o * 576 + k] = f2b(v);
}

// ---------------------------------------------------------------------------
// 4) Fused layer. Block = 512 threads = 8 waves, 16 nodes.
//    Phase 1: wave w aggregates nodes {2w, 2w+1} (R4 structure: 16 gathers in
//             flight, scalar if-tree routing), writes bf16 A-matrix rows to
//             LDS in MFMA A-layout: A_lds[m][k], m=node(16), k=0..575
//             (k=512..575 = node's own features for the root term).
//    Phase 2: MFMA 16x16x32 bf16. 8 waves = NT n-tiles x S k-splits
//             (NT=NOUT/16). Per chunk: 1 ds_read_b128 (A-frag) + 1 16B global
//             (B-frag from bf16 Wtb[o][k]) + 1 MFMA. ~72 MFMA/block replaces
//             ~1150 broadcast LDS reads + 9200 L1-line weight transactions.
//    Phase 3: k-split partial C reduce via LDS, bias (+ReLU), store.
// ---------------------------------------------------------------------------
template <int NOUT, bool RELU, typename OutT>
__global__ __launch_bounds__(512, 4) void k_layer(
        const ushort* __restrict__ xb, const int* __restrict__ offs,
        const int* __restrict__ cnt, const int* __restrict__ ssrc,
        const ushort* __restrict__ Wtb, const float* __restrict__ bias,
        OutT* __restrict__ out) {
    constexpr int NT = NOUT / 16;     // n-tiles
    constexpr int S  = 8 / NT;        // k-splits
    __shared__ __align__(16) ushort A_lds[16][584];   // 584 = 576 + 8 pad
    __shared__ f32x4 pc[6][64];                        // k-split partials

    const int tid = threadIdx.x;
    const int w = tid >> 6;
    const int f = tid & 63;
    const int node0 = blockIdx.x * 16;

    // ---- phase-2 wave assignment ----
    const int t = w % NT, q = w / NT;
    constexpr int cbase = 18 / S, crem = 18 % S;
    const int cs = q * cbase + (q < crem ? q : crem);
    const int ce = cs + cbase + (q < crem ? 1 : 0);
    const int n0 = t * 16;
    const ushort* bptr = Wtb + (n0 + (f & 15)) * 576 + ((f >> 4) * 8);
    short8 bcur = *(const short8*)(bptr + cs * 32);   // preload 1st B-frag early

    // ---- phase-1 metadata: lanes 0..15 -> offs/cnt for both nodes' 8 rels --
    int ov = 0, cv = 0;
    if (f < 16) {
        ov = offs[(node0 + w * 2) * N_RELS + f];
        cv = cnt [(node0 + w * 2) * N_RELS + f];
    }

    for (int nd = 0; nd < 2; ++nd) {
        const int m = w * 2 + nd;
        const int node = node0 + m;
        const int s0 = __builtin_amdgcn_readlane(ov, nd * 8);
        const int ct = __builtin_amdgcn_readlane(ov, nd * 8 + 7)
                     + __builtin_amdgcn_readlane(cv, nd * 8 + 7) - s0;

        float a[8];
        #pragma unroll
        for (int r = 0; r < 8; ++r) a[r] = 0.0f;

        for (int cb = 0; cb < ct; cb += 64) {
            int n = ct - cb;
            if (n > 64) n = 64;
            int pk = 15;                          // pad: rel=15, src=0
            if (f < n) pk = ssrc[s0 + cb + f];
            for (int e = 0; e < n; e += 16) {
                int pv[16];
                float xv[16];
                #pragma unroll
                for (int i = 0; i < 16; ++i)
                    pv[i] = __builtin_amdgcn_readlane(pk, e + i);   // SGPR
                #pragma unroll
                for (int i = 0; i < 16; ++i)
                    xv[i] = b2f(xb[(size_t)(pv[i] >> 4) * 64 + f]); // 16 indep gathers
                #pragma unroll
                for (int i = 0; i < 16; ++i) {
                    const int rl = pv[i] & 15;                      // scalar
                    if (rl < 4) {
                        if (rl < 2) { if (rl == 0) a[0] += xv[i]; else a[1] += xv[i]; }
                        else        { if (rl == 2) a[2] += xv[i]; else a[3] += xv[i]; }
                    } else if (rl < 8) {
                        if (rl < 6) { if (rl == 4) a[4] += xv[i]; else a[5] += xv[i]; }
                        else        { if (rl == 6) a[6] += xv[i]; else a[7] += xv[i]; }
                    }   // rl >= 8: pad, drop
                }
            }
        }

        // normalize + bf16 -> LDS A rows; root row = own features
        #pragma unroll
        for (int r = 0; r < 8; ++r) {
            int c = __builtin_amdgcn_readlane(cv, nd * 8 + r);
            float inv = 1.0f / (float)(c > 0 ? c : 1);
            A_lds[m][r * 64 + f] = f2b(a[r] * inv);
        }
        A_lds[m][512 + f] = xb[node * 64 + f];
    }
    __syncthreads();

    // ---- Phase 2: MFMA over this wave's chunks (software-pipelined B) ----
    f32x4 acc = (f32x4){0.0f, 0.0f, 0.0f, 0.0f};
    const ushort* aptr = &A_lds[f & 15][(f >> 4) * 8];
    for (int c = cs; c < ce; ++c) {
        short8 bnext = bcur;
        if (c + 1 < ce) bnext = *(const short8*)(bptr + (c + 1) * 32);
        short8 af = *(const short8*)(aptr + c * 32);
        acc = __builtin_amdgcn_mfma_f32_16x16x32_bf16(af, bcur, acc, 0, 0, 0);
        bcur = bnext;
    }

    // ---- Phase 3: reduce k-splits, bias (+ReLU), store ----
    if (q > 0) pc[w - NT][f] = acc;
    __syncthreads();
    if (q == 0) {
        #pragma unroll
        for (int j = 1; j < S; ++j) {
            f32x4 p = pc[t + NT * (j - 1)][f];
            acc.x += p.x; acc.y += p.y; acc.z += p.z; acc.w += p.w;
        }
        const int col = f & 15;
        const float bs = bias[n0 + col];
        const int mrow = (f >> 4) * 4;   // C/D: row=(lane>>4)*4+reg, col=lane&15
        #pragma unroll
        for (int i = 0; i < 4; ++i) {
            float v = acc[i] + bs;
            if (RELU) v = fmaxf(v, 0.0f);
            size_t oi = (size_t)(node0 + mrow + i) * NOUT + n0 + col;
            if constexpr (sizeof(OutT) == 2) out[oi] = (OutT)f2b(v);
            else                             out[oi] = (OutT)v;
        }
    }
}

// ---------------------------------------------------------------------------
// Launch
// ---------------------------------------------------------------------------
extern "C" void kernel_launch(void* const* d_in, const int* in_sizes, int n_in,
                              void* d_out, int out_size, void* d_ws, size_t ws_size,
                              hipStream_t stream) {
    const float* x     = (const float*)d_in[0];
    const int*   ei    = (const int*)d_in[1];
    const int*   et    = (const int*)d_in[2];
    const float* W1    = (const float*)d_in[3];
    const float* root1 = (const float*)d_in[4];
    const float* b1    = (const float*)d_in[5];
    const float* W2    = (const float*)d_in[6];
    const float* root2 = (const float*)d_in[7];
    const float* b2    = (const float*)d_in[8];
    float* out = (float*)d_out;

    const int* src = ei;            // edge_index[0]
    const int* dst = ei + N_EDGES;  // edge_index[1]

    // Workspace layout (~41.6 MB)
    char* ws = (char*)d_ws;
    int* cnt    = (int*)(ws);                                   // NSEG ints
    int* cursor = (int*)(ws + (size_t)NSEG * 4);                // NSEG ints
    int* offs   = (int*)(ws + (size_t)NSEG * 8);                // NSEG ints
    int* bsums  = (int*)(ws + (size_t)NSEG * 12);               // 1024 ints
    int* ssrc   = (int*)(ws + (size_t)NSEG * 12 + 4096);        // N_EDGES ints
    ushort* xb  = (ushort*)(ws + (size_t)NSEG * 12 + 4096 + (size_t)N_EDGES * 4); // N*64 bf16
    ushort* h1b = (ushort*)((char*)xb + (size_t)N_NODES * 64 * 2);                // N*64 bf16
    // Wt regions reuse cursor (dead after k_scatter, re-zeroed by memset)
    ushort* Wt1b = (ushort*)cursor;                              // 64*576 bf16 (73.7KB)
    ushort* Wt2b = (ushort*)((char*)cursor + 64 * 576 * 2);      // 32*576 bf16

    // zero cnt + cursor (adjacent)
    hipMemsetAsync(ws, 0, (size_t)NSEG * 8, stream);

    int eb = (N_EDGES + 255) / 256;
    k_hist<<<eb, 256, 0, stream>>>(dst, et, cnt);
    k_scanA<<<SCAN_NB, 256, 0, stream>>>(cnt, bsums);
    k_scanB<<<1, 1024, 0, stream>>>(bsums);
    k_scanC<<<SCAN_NB, 256, 0, stream>>>(cnt, bsums, offs);
    k_scatter<<<eb, 256, 0, stream>>>(src, dst, et, offs, cursor, ssrc);

    // cursor dead now; build bf16 transposed weights + bf16 features
    k_wt<<<(576 * 64 + 255) / 256, 256, 0, stream>>>(W1, root1, Wt1b, 64);
    k_wt<<<(576 * 32 + 255) / 256, 256, 0, stream>>>(W2, root2, Wt2b, 32);
    k_cvt<<<(N_NODES * 64 / 4 + 255) / 256, 256, 0, stream>>>(x, xb);

    // Layer 1: xb -> h1b (bf16, ReLU), NOUT=64
    k_layer<64, true, ushort><<<N_NODES / 16, 512, 0, stream>>>(
        xb, offs, cnt, ssrc, Wt1b, b1, h1b);
    // Layer 2: h1b -> out (fp32), NOUT=32
    k_layer<32, false, float><<<N_NODES / 16, 512, 0, stream>>>(
        h1b, offs, cnt, ssrc, Wt2b, b2, out);
}